// Round 1
// baseline (197.710 us; speedup 1.0000x reference)
//
#include <hip/hip_runtime.h>
#include <stdint.h>

#define N_ROWS  8192   // B*S = 4*2048
#define DIM     256
#define K_CODES 8192
#define SPLITK  8
#define KS      1024          // codes per split
#define NT      128           // codes per K-tile
#define LSLOTS  16            // per-row append slots in LDS
#define GSLOTS  12            // per-row-split survivor slots in ws
// acc-space (dot) margin: covers dist-bucket/2 (1.5e-5) + 2*bf16 dot err max
// (~4.5e-5) + dropped cnorm/2 (1.9e-6). 1e-4 leaves ~1.6x slack.
#define MARGIN_ACC 1.0e-4f

typedef unsigned long long u64;
typedef unsigned short u16;
typedef short s16x8 __attribute__((ext_vector_type(8)));   // 8 bf16 = 4 VGPR
typedef float f32x4 __attribute__((ext_vector_type(4)));

__device__ __forceinline__ u64 u64min(u64 a, u64 b) { return a < b ? a : b; }

// float -> bf16 bits, round-to-nearest-even (no NaN inputs here)
__device__ __forceinline__ u16 f2bf(float f) {
    unsigned u = __float_as_uint(f);
    u += 0x7fffu + ((u >> 16) & 1u);
    return (u16)(u >> 16);
}

// async 16B global->LDS (dest = wave-uniform base + lane*16, HW-added)
__device__ __forceinline__ void gld16(void* lds, const void* g) {
    __builtin_amdgcn_global_load_lds(
        (const __attribute__((address_space(1))) unsigned int*)g,
        (__attribute__((address_space(3))) unsigned int*)lds, 16, 0, 0);
}

// ---------------------------------------------------------------- kernel A
// Fused: bf16 conversion of z_e & cb + row norms. One wave per row.
__global__ __launch_bounds__(256) void vq_prep(const float* __restrict__ z_e,
                                               const float* __restrict__ cb,
                                               u16* __restrict__ zb,
                                               u16* __restrict__ cbb,
                                               float* __restrict__ xnorm,
                                               float* __restrict__ cnorm) {
    int wid  = (blockIdx.x * 256 + threadIdx.x) >> 6;
    int lane = threadIdx.x & 63;
    const float* src; u16* d16; float* dn;
    if (wid < N_ROWS) { src = z_e + (size_t)wid * DIM; d16 = zb + (size_t)wid * DIM; dn = xnorm + wid; }
    else              { int k = wid - N_ROWS;
                        src = cb  + (size_t)k   * DIM; d16 = cbb + (size_t)k * DIM; dn = cnorm + k; }
    float4 v = *(const float4*)(src + lane * 4);
    ushort4 h;
    h.x = f2bf(v.x); h.y = f2bf(v.y); h.z = f2bf(v.z); h.w = f2bf(v.w);
    *(ushort4*)(d16 + lane * 4) = h;
    float s = (v.x * v.x + v.y * v.y) + (v.z * v.z + v.w * v.w);
#pragma unroll
    for (int off = 1; off < 64; off <<= 1)
        s += __shfl_xor(s, off, 64);
    if (lane == 0) *dn = s;
}

// ---------------------------------------------------------------- kernel B
// bf16 MFMA dot GEMM + per-row running MAX of dot (argmin dist == argmax dot;
// xnorm constant per row, cnorm<=3.8e-6 folded into margin) + margin-append.
// Block: 128 rows x 1024 codes (one split), 4 waves 2x2.
//
// Pipeline restructure (vs. 2-barrier-per-chunk ancestor, MfmaUtil 14%):
//  * A (X rows, full K=256) lives in REGISTERS: af[4][8] = 128 VGPR, loaded
//    once per block straight from zb. The old LDS source-swizzle and the
//    read-side XOR cancel, so the fragment is a contiguous 16B load at
//    row*256 + s*32 + quad*8.  Deletes all X staging + X ds_reads + 1
//    barrier per chunk.
//  * C staged via global_load_lds w=16 into a 3-deep ring (T3+T4): per
//    chunk-iter i: STAGE(i+2) -> ds_read+MFMA buf[i%3] -> vmcnt(4) ->
//    s_barrier. Stages keep ~2 compute phases of latency cover; vmcnt never
//    drains to 0 in the main loop.  XOR source swizzle (chunk c^(row&7))
//    keeps the unpadded 128B-row layout conflict-free for ds_read_b128.
// LDS 65.5 KB -> 2 blocks/CU; ~240 VGPR -> 2 waves/SIMD (8 waves/CU).
__global__ __launch_bounds__(256, 2) void vq_mfma(const u16* __restrict__ zb,
                                                  const u16* __restrict__ cbb,
                                                  int* __restrict__ cand_cnt,
                                                  int* __restrict__ cand_idx) {
    __shared__ u16   Cs[3][128 * 64];   // 48 KB ring: [code-row][8 chunks of 8 bf16], swizzled
    __shared__ float lcd[128 * LSLOTS];
    __shared__ int   lci[128 * LSLOTS];
    __shared__ int   lcnt[128];
    __shared__ float gmaxs[2][128];

    const int tid   = threadIdx.x;
    const int lane  = tid & 63;
    const int wave  = tid >> 6;
    const int wm    = wave & 1;
    const int wn    = wave >> 1;
    const int quad  = lane >> 4;
    const int l16   = lane & 15;
    const int split = blockIdx.x;
    const int n0    = blockIdx.y * 128;

    if (tid < 128) lcnt[tid] = 0;

    // staging lane constants: lane covers (row srow8 of 8-group, dest chunk schunk)
    const int srow8  = lane >> 3;
    const int schunk = lane & 7;
    const int ssw    = (schunk ^ srow8) * 8;   // swizzled source chunk offset (shorts)
    const u16* csrc  = cbb + (size_t)split * KS * DIM + (size_t)srow8 * DIM + ssw;

    // ---- A fragments in registers for the whole block: af[i][s] covers
    // row n0+wm*64+i*16+l16, dims s*32 + quad*8 .. +7  (s = kc*2+ks)
    s16x8 af[4][8];
#pragma unroll
    for (int i = 0; i < 4; i++) {
        const u16* p = zb + (size_t)(n0 + wm * 64 + i * 16 + l16) * DIM + quad * 8;
#pragma unroll
        for (int s = 0; s < 8; s++)
            af[i][s] = *(const s16x8*)(p + s * 32);
    }

    // stage chunk-iter s (code-tile s>>2, 64-dim chunk s&3) into Cs[bw]
    auto STAGE = [&](int s, int bw) {
        const u16* src = csrc + (size_t)(s >> 2) * (NT * DIM) + (s & 3) * 64;
#pragma unroll
        for (int t = 0; t < 4; t++) {
            int rg = wave * 4 + t;            // 8-row code group, wave-uniform
            gld16(&Cs[bw][rg * 512], src + (size_t)rg * (8 * DIM));
        }
    };

    float runmax[16];
#pragma unroll
    for (int t = 0; t < 16; t++) runmax[t] = -3.0e38f;

    // prologue: fill ring slots 0,1; vmcnt(4) drains A-loads + stage(0),
    // leaves stage(1)'s 4 loads in flight.
    STAGE(0, 0);
    STAGE(1, 1);
    asm volatile("s_waitcnt vmcnt(4)" ::: "memory");
    __builtin_amdgcn_s_barrier();

    int bufR = 0, bufW = 2;

    for (int kt = 0; kt < 8; kt++) {
        const int kbase = split * KS + kt * NT;
        f32x4 acc[4][4];
#pragma unroll
        for (int i = 0; i < 4; i++)
#pragma unroll
            for (int j = 0; j < 4; j++)
#pragma unroll
                for (int e = 0; e < 4; e++) acc[i][j][e] = 0.0f;

#pragma unroll
        for (int kc = 0; kc < 4; kc++) {     // 64-dim chunks, flat iter index
            const int it = (kt << 2) | kc;
            if (it < 30) STAGE(it + 2, bufW);     // 2-ahead prefetch

            const u16* cbuf = &Cs[bufR][0];       // staged(it); ready per barrier(it-1)
#pragma unroll
            for (int ks = 0; ks < 2; ks++) {
                s16x8 bfr[4];
#pragma unroll
                for (int j = 0; j < 4; j++)
                    bfr[j] = *(const s16x8*)&cbuf[(wn * 64 + j * 16 + l16) * 64 +
                                                  (((ks << 2) | quad) ^ (l16 & 7)) * 8];
#pragma unroll
                for (int i = 0; i < 4; i++)
#pragma unroll
                    for (int j = 0; j < 4; j++)
                        acc[i][j] = __builtin_amdgcn_mfma_f32_16x16x32_bf16(
                            af[i][kc * 2 + ks], bfr[j], acc[i][j], 0, 0, 0);
            }

            // end-of-iter: drain stage(it+1) (leave stage(it+2) in flight),
            // then barrier => next iter's reads safe + ring overwrite safe.
            if (it < 30) {
                asm volatile("s_waitcnt vmcnt(4)" ::: "memory");
                __builtin_amdgcn_s_barrier();
            } else if (it == 30) {
                asm volatile("s_waitcnt vmcnt(0)" ::: "memory");
                __builtin_amdgcn_s_barrier();
            }                                      // it==31: nothing outstanding
            bufR = bufR == 2 ? 0 : bufR + 1;
            bufW = bufW == 2 ? 0 : bufW + 1;
        }

        // ---- epilogue: in-wave row-tile max, runmax update, margin appends
#pragma unroll
        for (int i = 0; i < 4; i++)
#pragma unroll
            for (int r = 0; r < 4; r++) {
                float m = fmaxf(fmaxf(acc[i][0][r], acc[i][1][r]),
                                fmaxf(acc[i][2][r], acc[i][3][r]));
                m = fmaxf(m, __shfl_xor(m, 1, 64));
                m = fmaxf(m, __shfl_xor(m, 2, 64));
                m = fmaxf(m, __shfl_xor(m, 4, 64));
                m = fmaxf(m, __shfl_xor(m, 8, 64));
                runmax[i * 4 + r] = fmaxf(runmax[i * 4 + r], m);
                float thr = runmax[i * 4 + r] - MARGIN_ACC;
                int rl = wm * 64 + i * 16 + quad * 4 + r;
#pragma unroll
                for (int j = 0; j < 4; j++) {
                    float d = acc[i][j][r];
                    if (d >= thr) {
                        int pos = atomicAdd(&lcnt[rl], 1);
                        if (pos < LSLOTS) {
                            lcd[rl * LSLOTS + pos] = d;
                            lci[rl * LSLOTS + pos] = kbase + wn * 64 + j * 16 + l16;
                        }
                    }
                }
            }
    }

    if (l16 == 0) {
#pragma unroll
        for (int i = 0; i < 4; i++)
#pragma unroll
            for (int r = 0; r < 4; r++)
                gmaxs[wn][wm * 64 + i * 16 + quad * 4 + r] = runmax[i * 4 + r];
    }
    __syncthreads();

    // filter appends vs final row max (winner guaranteed in the superset)
    if (tid < 128) {
        int n   = n0 + tid;
        int cnt = lcnt[tid]; if (cnt > LSLOTS) cnt = LSLOTS;
        float thrf = fmaxf(gmaxs[0][tid], gmaxs[1][tid]) - MARGIN_ACC;
        int base = (n * SPLITK + split) * GSLOTS;
        int w = 0;
        for (int s = 0; s < cnt && w < GSLOTS; s++)
            if (lcd[tid * LSLOTS + s] >= thrf)
                cand_idx[base + w++] = lci[tid * LSLOTS + s];
        cand_cnt[n * SPLITK + split] = w;
    }
}

// ---------------------------------------------------------------- kernel C
// Exact fp32 recheck (association identical to the R2/R3-passing version:
// sequential fmaf d=0..255, fmaf(-2,m,xn)+cn), lexicographic (dist,idx) min;
// then gather + z_q_st + rowloss. One wave per row.
__global__ __launch_bounds__(256) void vq_finalize(const float* __restrict__ z_e,
                                                   const float* __restrict__ cb,
                                                   const float* __restrict__ xnorm,
                                                   const float* __restrict__ cnorm,
                                                   const int* __restrict__ cand_cnt,
                                                   const int* __restrict__ cand_idx,
                                                   float* __restrict__ out_zq,
                                                   float* __restrict__ out_idx,
                                                   float* __restrict__ rowloss) {
    const int n    = blockIdx.x * 4 + (threadIdx.x >> 6);
    const int lane = threadIdx.x & 63;

    int myidx = -1;
    int t = 0;
#pragma unroll
    for (int s = 0; s < SPLITK; s++) {
        int c = cand_cnt[n * SPLITK + s];
        if (lane >= t && lane < t + c)
            myidx = cand_idx[(n * SPLITK + s) * GSLOTS + (lane - t)];
        t += c;
    }

    u64 key = ~0ULL;
    if (myidx >= 0) {
        const float* xr = z_e + (size_t)n * DIM;
        const float* cr = cb + (size_t)myidx * DIM;
        float acc = 0.0f;
#pragma unroll 8
        for (int d = 0; d < DIM; d++)
            acc = __builtin_fmaf(xr[d], cr[d], acc);
        float dist = __builtin_fmaf(-2.0f, acc, xnorm[n]) + cnorm[myidx];
        key = ((u64)__float_as_uint(dist) << 32) | (unsigned)myidx;
    }
#pragma unroll
    for (int off = 1; off < 64; off <<= 1)
        key = u64min(key, __shfl_xor(key, off, 64));

    int idx = (int)(unsigned)(key & 0xffffffffu);
    if (key == ~0ULL) idx = 0;  // unreachable safety

    float4 x = *(const float4*)(z_e + (size_t)n * DIM + lane * 4);
    float4 c = *(const float4*)(cb + (size_t)idx * DIM + lane * 4);
    float4 st;
    st.x = x.x + (c.x - x.x); st.y = x.y + (c.y - x.y);
    st.z = x.z + (c.z - x.z); st.w = x.w + (c.w - x.w);
    *(float4*)(out_zq + (size_t)n * DIM + lane * 4) = st;

    float d0 = x.x - c.x, d1 = x.y - c.y, d2 = x.z - c.z, d3 = x.w - c.w;
    float s2 = (d0 * d0 + d1 * d1) + (d2 * d2 + d3 * d3);
#pragma unroll
    for (int off = 1; off < 64; off <<= 1)
        s2 += __shfl_xor(s2, off, 64);
    if (lane == 0) {
        rowloss[n] = s2;
        out_idx[n] = (float)idx;
    }
}

// ---------------------------------------------------------------- kernel D
__global__ __launch_bounds__(256) void vq_loss(const float* __restrict__ rowloss,
                                               float* __restrict__ out_loss) {
    __shared__ double sd[256];
    double s = 0.0;
    for (int i = threadIdx.x; i < N_ROWS; i += 256) s += (double)rowloss[i];
    sd[threadIdx.x] = s;
    __syncthreads();
    for (int off = 128; off; off >>= 1) {
        if (threadIdx.x < off) sd[threadIdx.x] += sd[threadIdx.x + off];
        __syncthreads();
    }
    if (threadIdx.x == 0) {
        double mean = sd[0] / (double)((size_t)N_ROWS * DIM);
        out_loss[0] = (float)(1.25 * mean);
    }
}

// ---------------------------------------------------------------- launch
extern "C" void kernel_launch(void* const* d_in, const int* in_sizes, int n_in,
                              void* d_out, int out_size, void* d_ws, size_t ws_size,
                              hipStream_t stream) {
    const float* z_e = (const float*)d_in[0];
    const float* cb  = (const float*)d_in[1];

    float* out   = (float*)d_out;
    float* zq    = out;
    float* oidx  = out + (size_t)N_ROWS * DIM;
    float* oloss = oidx + N_ROWS;

    // ws layout (~11.9 MB):
    //   zb   bf16[8192*256]  4 MB
    //   cbb  bf16[8192*256]  4 MB
    //   xnorm/cnorm/rowloss  3*32 KB
    //   cand_cnt int[8192*8] 256 KB
    //   cand_idx int[8192*8*GSLOTS] 3 MB
    u16*   zb       = (u16*)d_ws;
    u16*   cbb      = zb + (size_t)N_ROWS * DIM;
    float* xnorm    = (float*)(cbb + (size_t)K_CODES * DIM);
    float* cnorm    = xnorm + N_ROWS;
    float* rowloss  = cnorm + K_CODES;
    int*   cand_cnt = (int*)(rowloss + N_ROWS);
    int*   cand_idx = cand_cnt + N_ROWS * SPLITK;

    vq_prep    <<<(N_ROWS + K_CODES) / 4, 256, 0, stream>>>(z_e, cb, zb, cbb, xnorm, cnorm);
    // grid (split, mtile): linear%8 == split -> each split pinned to one XCD,
    // its 0.5MB bf16 codebook split + 4MB zb stay L2-resident.
    vq_mfma    <<<dim3(SPLITK, N_ROWS / 128), 256, 0, stream>>>(zb, cbb, cand_cnt, cand_idx);
    vq_finalize<<<N_ROWS / 4, 256, 0, stream>>>(z_e, cb, xnorm, cnorm, cand_cnt, cand_idx, zq, oidx, rowloss);
    vq_loss    <<<1, 256, 0, stream>>>(rowloss, oloss);
}

// Round 2
// 180.500 us; speedup vs baseline: 1.0953x; 1.0953x over previous
//
#include <hip/hip_runtime.h>
#include <stdint.h>

#define N_ROWS  8192   // B*S = 4*2048
#define DIM     256
#define K_CODES 8192
#define SPLITK  8
#define KS      1024          // codes per split
#define NT      128           // codes per K-tile
#define LSLOTS  16            // per-row append slots in LDS
#define GSLOTS  12            // per-row-split survivor slots in ws
// acc-space (dot) margin: covers dist-bucket/2 (1.5e-5) + 2*bf16 dot err max
// (~4.5e-5) + dropped cnorm/2 (1.9e-6). 1e-4 leaves ~1.6x slack.
#define MARGIN_ACC 1.0e-4f

typedef unsigned long long u64;
typedef unsigned short u16;
typedef short s16x8 __attribute__((ext_vector_type(8)));   // 8 bf16 = 4 VGPR
typedef float f32x4 __attribute__((ext_vector_type(4)));

__device__ __forceinline__ u64 u64min(u64 a, u64 b) { return a < b ? a : b; }

// float -> bf16 bits, round-to-nearest-even (no NaN inputs here)
__device__ __forceinline__ u16 f2bf(float f) {
    unsigned u = __float_as_uint(f);
    u += 0x7fffu + ((u >> 16) & 1u);
    return (u16)(u >> 16);
}

// async 16B global->LDS (dest = wave-uniform base + lane*16, HW-added)
__device__ __forceinline__ void gld16(void* lds, const void* g) {
    __builtin_amdgcn_global_load_lds(
        (const __attribute__((address_space(1))) unsigned int*)g,
        (__attribute__((address_space(3))) unsigned int*)lds, 16, 0, 0);
}

// ---------------------------------------------------------------- kernel A
// Fused: bf16 conversion of z_e & cb + row norms. One wave per row.
__global__ __launch_bounds__(256) void vq_prep(const float* __restrict__ z_e,
                                               const float* __restrict__ cb,
                                               u16* __restrict__ zb,
                                               u16* __restrict__ cbb,
                                               float* __restrict__ xnorm,
                                               float* __restrict__ cnorm) {
    int wid  = (blockIdx.x * 256 + threadIdx.x) >> 6;
    int lane = threadIdx.x & 63;
    const float* src; u16* d16; float* dn;
    if (wid < N_ROWS) { src = z_e + (size_t)wid * DIM; d16 = zb + (size_t)wid * DIM; dn = xnorm + wid; }
    else              { int k = wid - N_ROWS;
                        src = cb  + (size_t)k   * DIM; d16 = cbb + (size_t)k * DIM; dn = cnorm + k; }
    float4 v = *(const float4*)(src + lane * 4);
    ushort4 h;
    h.x = f2bf(v.x); h.y = f2bf(v.y); h.z = f2bf(v.z); h.w = f2bf(v.w);
    *(ushort4*)(d16 + lane * 4) = h;
    float s = (v.x * v.x + v.y * v.y) + (v.z * v.z + v.w * v.w);
#pragma unroll
    for (int off = 1; off < 64; off <<= 1)
        s += __shfl_xor(s, off, 64);
    if (lane == 0) *dn = s;
}

// ---------------------------------------------------------------- kernel B
// bf16 MFMA dot GEMM + per-row running MAX of dot (argmin dist == argmax dot;
// xnorm constant per row, cnorm<=3.8e-6 folded into margin) + margin-append.
// Block: 128 rows x 1024 codes (one split), 4 waves, each a 32-row slab.
//
// R2 restructure (vs. R1, which SPILLED: af[4][8]=128 VGPR -> 128-cap +
// 11 MB scratch writes + 183us cold dispatch):
//  * 1x4 wave tiling: wave w owns rows w*32..w*32+31 x ALL 128 codes of the
//    tile. af[2][8] = 64 VGPR (half of R1), acc[2][8] = 64. Each row's
//    running max / appends live entirely in one wave -> single gmaxs[].
//  * A (32 rows, full K=256) in registers, loaded once per block from zb
//    (contiguous 16B at row*256 + s*32 + quad*8; LDS swizzles cancel).
//  * C staged via global_load_lds w=16 into a 3-deep ring (T3+T4): iter i:
//    STAGE(i+2) -> ds_read+MFMA buf[i%3] -> vmcnt(4) -> s_barrier. vmcnt
//    never drains to 0 in the main loop; XOR source swizzle (chunk c^(row&7))
//    keeps the unpadded 128B-row layout conflict-free for ds_read_b128.
// LDS ~65 KB -> 2 blocks/CU; ~180 VGPR -> 2 waves/SIMD (8 waves/CU), NO spill.
__global__ __launch_bounds__(256, 2) void vq_mfma(const u16* __restrict__ zb,
                                                  const u16* __restrict__ cbb,
                                                  int* __restrict__ cand_cnt,
                                                  int* __restrict__ cand_idx) {
    __shared__ u16   Cs[3][128 * 64];   // 48 KB ring: [code-row][8 chunks of 8 bf16], swizzled
    __shared__ float lcd[128 * LSLOTS];
    __shared__ int   lci[128 * LSLOTS];
    __shared__ int   lcnt[128];
    __shared__ float gmaxs[128];

    const int tid   = threadIdx.x;
    const int lane  = tid & 63;
    const int wave  = tid >> 6;
    const int quad  = lane >> 4;
    const int l16   = lane & 15;
    const int split = blockIdx.x;
    const int n0    = blockIdx.y * 128;

    if (tid < 128) lcnt[tid] = 0;

    // staging lane constants: lane covers (row srow8 of 8-group, dest chunk schunk)
    const int srow8  = lane >> 3;
    const int schunk = lane & 7;
    const int ssw    = (schunk ^ srow8) * 8;   // swizzled source chunk offset (shorts)
    const u16* csrc  = cbb + (size_t)split * KS * DIM + (size_t)srow8 * DIM + ssw;

    // ---- A fragments in registers for the whole block: af[i][s] covers
    // row n0+wave*32+i*16+l16, dims s*32 + quad*8 .. +7  (s = kc*2+ks)
    s16x8 af[2][8];
#pragma unroll
    for (int i = 0; i < 2; i++) {
        const u16* p = zb + (size_t)(n0 + wave * 32 + i * 16 + l16) * DIM + quad * 8;
#pragma unroll
        for (int s = 0; s < 8; s++)
            af[i][s] = *(const s16x8*)(p + s * 32);
    }

    // stage chunk-iter s (code-tile s>>2, 64-dim chunk s&3) into Cs[bw]
    auto STAGE = [&](int s, int bw) {
        const u16* src = csrc + (size_t)(s >> 2) * (NT * DIM) + (s & 3) * 64;
#pragma unroll
        for (int t = 0; t < 4; t++) {
            int rg = wave * 4 + t;            // 8-row code group, wave-uniform
            gld16(&Cs[bw][rg * 512], src + (size_t)rg * (8 * DIM));
        }
    };

    float runmax[8];
#pragma unroll
    for (int t = 0; t < 8; t++) runmax[t] = -3.0e38f;

    // prologue: fill ring slots 0,1; vmcnt(4) drains A-loads + stage(0),
    // leaves stage(1)'s 4 loads in flight.
    STAGE(0, 0);
    STAGE(1, 1);
    asm volatile("s_waitcnt vmcnt(4)" ::: "memory");
    __builtin_amdgcn_s_barrier();

    int bufR = 0, bufW = 2;

    for (int kt = 0; kt < 8; kt++) {
        const int kbase = split * KS + kt * NT;
        f32x4 acc[2][8];
#pragma unroll
        for (int i = 0; i < 2; i++)
#pragma unroll
            for (int j = 0; j < 8; j++)
#pragma unroll
                for (int e = 0; e < 4; e++) acc[i][j][e] = 0.0f;

#pragma unroll
        for (int kc = 0; kc < 4; kc++) {     // 64-dim chunks, flat iter index
            const int it = (kt << 2) | kc;
            if (it < 30) STAGE(it + 2, bufW);     // 2-ahead prefetch

            const u16* cbuf = &Cs[bufR][0];       // staged(it); ready per barrier(it-1)
#pragma unroll
            for (int ks = 0; ks < 2; ks++) {
                s16x8 bfr[8];
#pragma unroll
                for (int j = 0; j < 8; j++)
                    bfr[j] = *(const s16x8*)&cbuf[(j * 16 + l16) * 64 +
                                                  (((ks << 2) | quad) ^ (l16 & 7)) * 8];
#pragma unroll
                for (int i = 0; i < 2; i++)
#pragma unroll
                    for (int j = 0; j < 8; j++)
                        acc[i][j] = __builtin_amdgcn_mfma_f32_16x16x32_bf16(
                            af[i][kc * 2 + ks], bfr[j], acc[i][j], 0, 0, 0);
            }

            // end-of-iter: drain stage(it+1) (leave stage(it+2) in flight),
            // then barrier => next iter's reads safe + ring overwrite safe.
            if (it < 30) {
                asm volatile("s_waitcnt vmcnt(4)" ::: "memory");
                __builtin_amdgcn_s_barrier();
            } else if (it == 30) {
                asm volatile("s_waitcnt vmcnt(0)" ::: "memory");
                __builtin_amdgcn_s_barrier();
            }                                      // it==31: nothing outstanding
            bufR = bufR == 2 ? 0 : bufR + 1;
            bufW = bufW == 2 ? 0 : bufW + 1;
        }

        // ---- epilogue: in-wave row max over 8 code-frags, runmax update,
        // margin appends. Row rl = wave*32 + i*16 + quad*4 + r, owned by this wave.
#pragma unroll
        for (int i = 0; i < 2; i++)
#pragma unroll
            for (int r = 0; r < 4; r++) {
                float m = fmaxf(fmaxf(fmaxf(acc[i][0][r], acc[i][1][r]),
                                      fmaxf(acc[i][2][r], acc[i][3][r])),
                                fmaxf(fmaxf(acc[i][4][r], acc[i][5][r]),
                                      fmaxf(acc[i][6][r], acc[i][7][r])));
                m = fmaxf(m, __shfl_xor(m, 1, 64));
                m = fmaxf(m, __shfl_xor(m, 2, 64));
                m = fmaxf(m, __shfl_xor(m, 4, 64));
                m = fmaxf(m, __shfl_xor(m, 8, 64));
                runmax[i * 4 + r] = fmaxf(runmax[i * 4 + r], m);
                float thr = runmax[i * 4 + r] - MARGIN_ACC;
                int rl = wave * 32 + i * 16 + quad * 4 + r;
#pragma unroll
                for (int j = 0; j < 8; j++) {
                    float d = acc[i][j][r];
                    if (d >= thr) {
                        int pos = atomicAdd(&lcnt[rl], 1);
                        if (pos < LSLOTS) {
                            lcd[rl * LSLOTS + pos] = d;
                            lci[rl * LSLOTS + pos] = kbase + j * 16 + l16;
                        }
                    }
                }
            }
    }

    if (l16 == 0) {
#pragma unroll
        for (int i = 0; i < 2; i++)
#pragma unroll
            for (int r = 0; r < 4; r++)
                gmaxs[wave * 32 + i * 16 + quad * 4 + r] = runmax[i * 4 + r];
    }
    __syncthreads();

    // filter appends vs final row max (winner guaranteed in the superset)
    if (tid < 128) {
        int n   = n0 + tid;
        int cnt = lcnt[tid]; if (cnt > LSLOTS) cnt = LSLOTS;
        float thrf = gmaxs[tid] - MARGIN_ACC;
        int base = (n * SPLITK + split) * GSLOTS;
        int w = 0;
        for (int s = 0; s < cnt && w < GSLOTS; s++)
            if (lcd[tid * LSLOTS + s] >= thrf)
                cand_idx[base + w++] = lci[tid * LSLOTS + s];
        cand_cnt[n * SPLITK + split] = w;
    }
}

// ---------------------------------------------------------------- kernel C
// Exact fp32 recheck (association identical to the R2/R3-passing version:
// sequential fmaf d=0..255, fmaf(-2,m,xn)+cn), lexicographic (dist,idx) min;
// then gather + z_q_st + rowloss. One wave per row.
__global__ __launch_bounds__(256) void vq_finalize(const float* __restrict__ z_e,
                                                   const float* __restrict__ cb,
                                                   const float* __restrict__ xnorm,
                                                   const float* __restrict__ cnorm,
                                                   const int* __restrict__ cand_cnt,
                                                   const int* __restrict__ cand_idx,
                                                   float* __restrict__ out_zq,
                                                   float* __restrict__ out_idx,
                                                   float* __restrict__ rowloss) {
    const int n    = blockIdx.x * 4 + (threadIdx.x >> 6);
    const int lane = threadIdx.x & 63;

    int myidx = -1;
    int t = 0;
#pragma unroll
    for (int s = 0; s < SPLITK; s++) {
        int c = cand_cnt[n * SPLITK + s];
        if (lane >= t && lane < t + c)
            myidx = cand_idx[(n * SPLITK + s) * GSLOTS + (lane - t)];
        t += c;
    }

    u64 key = ~0ULL;
    if (myidx >= 0) {
        const float* xr = z_e + (size_t)n * DIM;
        const float* cr = cb + (size_t)myidx * DIM;
        float acc = 0.0f;
#pragma unroll 8
        for (int d = 0; d < DIM; d++)
            acc = __builtin_fmaf(xr[d], cr[d], acc);
        float dist = __builtin_fmaf(-2.0f, acc, xnorm[n]) + cnorm[myidx];
        key = ((u64)__float_as_uint(dist) << 32) | (unsigned)myidx;
    }
#pragma unroll
    for (int off = 1; off < 64; off <<= 1)
        key = u64min(key, __shfl_xor(key, off, 64));

    int idx = (int)(unsigned)(key & 0xffffffffu);
    if (key == ~0ULL) idx = 0;  // unreachable safety

    float4 x = *(const float4*)(z_e + (size_t)n * DIM + lane * 4);
    float4 c = *(const float4*)(cb + (size_t)idx * DIM + lane * 4);
    float4 st;
    st.x = x.x + (c.x - x.x); st.y = x.y + (c.y - x.y);
    st.z = x.z + (c.z - x.z); st.w = x.w + (c.w - x.w);
    *(float4*)(out_zq + (size_t)n * DIM + lane * 4) = st;

    float d0 = x.x - c.x, d1 = x.y - c.y, d2 = x.z - c.z, d3 = x.w - c.w;
    float s2 = (d0 * d0 + d1 * d1) + (d2 * d2 + d3 * d3);
#pragma unroll
    for (int off = 1; off < 64; off <<= 1)
        s2 += __shfl_xor(s2, off, 64);
    if (lane == 0) {
        rowloss[n] = s2;
        out_idx[n] = (float)idx;
    }
}

// ---------------------------------------------------------------- kernel D
__global__ __launch_bounds__(256) void vq_loss(const float* __restrict__ rowloss,
                                               float* __restrict__ out_loss) {
    __shared__ double sd[256];
    double s = 0.0;
    for (int i = threadIdx.x; i < N_ROWS; i += 256) s += (double)rowloss[i];
    sd[threadIdx.x] = s;
    __syncthreads();
    for (int off = 128; off; off >>= 1) {
        if (threadIdx.x < off) sd[threadIdx.x] += sd[threadIdx.x + off];
        __syncthreads();
    }
    if (threadIdx.x == 0) {
        double mean = sd[0] / (double)((size_t)N_ROWS * DIM);
        out_loss[0] = (float)(1.25 * mean);
    }
}

// ---------------------------------------------------------------- launch
extern "C" void kernel_launch(void* const* d_in, const int* in_sizes, int n_in,
                              void* d_out, int out_size, void* d_ws, size_t ws_size,
                              hipStream_t stream) {
    const float* z_e = (const float*)d_in[0];
    const float* cb  = (const float*)d_in[1];

    float* out   = (float*)d_out;
    float* zq    = out;
    float* oidx  = out + (size_t)N_ROWS * DIM;
    float* oloss = oidx + N_ROWS;

    // ws layout (~11.9 MB):
    //   zb   bf16[8192*256]  4 MB
    //   cbb  bf16[8192*256]  4 MB
    //   xnorm/cnorm/rowloss  3*32 KB
    //   cand_cnt int[8192*8] 256 KB
    //   cand_idx int[8192*8*GSLOTS] 3 MB
    u16*   zb       = (u16*)d_ws;
    u16*   cbb      = zb + (size_t)N_ROWS * DIM;
    float* xnorm    = (float*)(cbb + (size_t)K_CODES * DIM);
    float* cnorm    = xnorm + N_ROWS;
    float* rowloss  = cnorm + K_CODES;
    int*   cand_cnt = (int*)(rowloss + N_ROWS);
    int*   cand_idx = cand_cnt + N_ROWS * SPLITK;

    vq_prep    <<<(N_ROWS + K_CODES) / 4, 256, 0, stream>>>(z_e, cb, zb, cbb, xnorm, cnorm);
    // grid (split, mtile): linear%8 == split -> each split pinned to one XCD,
    // its 0.5MB bf16 codebook split + 4MB zb stay L2-resident.
    vq_mfma    <<<dim3(SPLITK, N_ROWS / 128), 256, 0, stream>>>(zb, cbb, cand_cnt, cand_idx);
    vq_finalize<<<N_ROWS / 4, 256, 0, stream>>>(z_e, cb, xnorm, cnorm, cand_cnt, cand_idx, zq, oidx, rowloss);
    vq_loss    <<<1, 256, 0, stream>>>(rowloss, oloss);
}